// Round 1
// baseline (69.724 us; speedup 1.0000x reference)
//
#include <hip/hip_runtime.h>
#include <hip/hip_bf16.h>

// Problem: EnhancedBCMLayer — block-circulant matmul.
// out[B, f*16+t] = sum_g sum_s iv[f,g,s] * x[B, g*16 + ((t-s)&15)] + b[f*16+t]
// == dense GEMM: out = X (4096x2048) @ W^T (2048x2048) + b,
//    W[f*16+t][g*16+u] = iv[f, g, (t-u)&15]

#define M_DIM 4096
#define N_DIM 2048
#define K_DIM 2048

typedef __attribute__((ext_vector_type(8))) short bf16x8;
typedef __attribute__((ext_vector_type(4))) float f32x4;

typedef const __attribute__((address_space(1))) void gvoid_t;
typedef __attribute__((address_space(3))) void lvoid_t;

// fp32 -> bf16 round-to-nearest-even (finite inputs only)
__device__ __forceinline__ unsigned int f2bf(float f) {
  unsigned int u = __float_as_uint(f);
  return (u + 0x7fffu + ((u >> 16) & 1u)) >> 16;
}

// ---------------- prologue 1: X fp32 -> bf16 (8 elems / thread) ----------------
__global__ __launch_bounds__(256) void cvt_x_kernel(const float* __restrict__ x,
                                                    unsigned short* __restrict__ xb) {
  int idx = blockIdx.x * 256 + threadIdx.x;  // one per 8 floats; grid sized exactly
  const float4* x4 = (const float4*)x;
  float4 a = x4[idx * 2 + 0];
  float4 c = x4[idx * 2 + 1];
  uint4 o;
  o.x = f2bf(a.x) | (f2bf(a.y) << 16);
  o.y = f2bf(a.z) | (f2bf(a.w) << 16);
  o.z = f2bf(c.x) | (f2bf(c.y) << 16);
  o.w = f2bf(c.z) | (f2bf(c.w) << 16);
  ((uint4*)xb)[idx] = o;
}

// ---------------- prologue 2: expand circulant blocks into dense bf16 W [N][K] ----------------
__global__ __launch_bounds__(256) void build_w_kernel(const float* __restrict__ iv,
                                                      unsigned short* __restrict__ W) {
  int idx = blockIdx.x * 256 + threadIdx.x;  // one per 8 weights (same o-row)
  int o  = idx >> 8;            // output row 0..2047
  int i0 = (idx & 255) * 8;     // col start (multiple of 8)
  int f = o >> 4, t = o & 15;
  int g = i0 >> 4, u0 = i0 & 15;  // u0 = 0 or 8
  const float* row = iv + (f * 128 + g) * 16;
  unsigned int p[4];
#pragma unroll
  for (int j = 0; j < 4; ++j) {
    unsigned int lo = f2bf(row[(t - (u0 + 2 * j + 0)) & 15]);
    unsigned int hi = f2bf(row[(t - (u0 + 2 * j + 1)) & 15]);
    p[j] = lo | (hi << 16);
  }
  uint4 o4 = make_uint4(p[0], p[1], p[2], p[3]);
  ((uint4*)W)[idx] = o4;
}

// ---------------- main GEMM: C = A(bf16, MxK) * B(bf16, NxK)^T + bias, fp32 out ----------------
// m97 structure: 128x128 tile, BK=32, 4 waves (2x2), each wave 64x64 (4x4 frags of 16x16x32).
__global__ __launch_bounds__(256) void gemm_bias_kernel(const unsigned short* __restrict__ A,
                                                        const unsigned short* __restrict__ B,
                                                        const float* __restrict__ bias,
                                                        float* __restrict__ C) {
  __shared__ short As[128 * 32];  // 8 KB, linear (global_load_lds requires linear dest)
  __shared__ short Bs[128 * 32];  // 8 KB

  const int tid  = threadIdx.x;
  const int lane = tid & 63;
  const int wid  = tid >> 6;
  const int bn = blockIdx.x;   // N tile (0..15)
  const int bm = blockIdx.y;   // M tile (0..31)
  const int wr = wid >> 1;     // wave row 0..1 (64 rows each)
  const int wc = wid & 1;      // wave col 0..1 (64 cols each)

  f32x4 acc[4][4] = {};

  // Staging: each wave fills 2 KB of each tile per K-step via 2x global_load_lds(16B).
  // LDS byte layout [row][32 bf16 cols]: wave w instr i covers rows w*32+i*16 .. +15.
  const int srow = wid * 32 + (lane >> 2);            // + 16 for the second instr
  const unsigned short* Ag = A + (size_t)(bm * 128 + srow) * K_DIM + (lane & 3) * 8;
  const unsigned short* Bg = B + (size_t)(bn * 128 + srow) * K_DIM + (lane & 3) * 8;
  char* AsB = (char*)As + wid * 2048;
  char* BsB = (char*)Bs + wid * 2048;

  const int kch = (lane >> 4) * 8;          // K-chunk within fragment
  const int rA  = wr * 64 + (lane & 15);    // A fragment row (M-local)
  const int rB  = wc * 64 + (lane & 15);    // B fragment row (N-local)

  for (int k0 = 0; k0 < K_DIM; k0 += 32) {
    __builtin_amdgcn_global_load_lds((gvoid_t*)(Ag + k0),              (lvoid_t*)(AsB),        16, 0, 0);
    __builtin_amdgcn_global_load_lds((gvoid_t*)(Ag + 16 * K_DIM + k0), (lvoid_t*)(AsB + 1024), 16, 0, 0);
    __builtin_amdgcn_global_load_lds((gvoid_t*)(Bg + k0),              (lvoid_t*)(BsB),        16, 0, 0);
    __builtin_amdgcn_global_load_lds((gvoid_t*)(Bg + 16 * K_DIM + k0), (lvoid_t*)(BsB + 1024), 16, 0, 0);
    __syncthreads();  // drains vmcnt -> LDS tile ready

    bf16x8 af[4], bfr[4];
#pragma unroll
    for (int m = 0; m < 4; ++m)
      af[m] = *(const bf16x8*)&As[(rA + m * 16) * 32 + kch];
#pragma unroll
    for (int n = 0; n < 4; ++n)
      bfr[n] = *(const bf16x8*)&Bs[(rB + n * 16) * 32 + kch];

#pragma unroll
    for (int m = 0; m < 4; ++m)
#pragma unroll
      for (int n = 0; n < 4; ++n)
        acc[m][n] = __builtin_amdgcn_mfma_f32_16x16x32_bf16(af[m], bfr[n], acc[m][n], 0, 0, 0);

    __syncthreads();  // protect LDS before next stage
  }

  // Epilogue: C/D layout col = lane&15, row = (lane>>4)*4 + reg  [m89-verified]
  const int cl   = lane & 15;
  const int rb   = (lane >> 4) * 4;
  const int row0 = bm * 128 + wr * 64 + rb;
  const int col0 = bn * 128 + wc * 64 + cl;
#pragma unroll
  for (int n = 0; n < 4; ++n) {
    float bv = bias[col0 + n * 16];
#pragma unroll
    for (int m = 0; m < 4; ++m) {
#pragma unroll
      for (int j = 0; j < 4; ++j) {
        C[(size_t)(row0 + m * 16 + j) * N_DIM + (col0 + n * 16)] = acc[m][n][j] + bv;
      }
    }
  }
}

// ---------------- fallback (only if ws too small): direct fp32 ----------------
__global__ __launch_bounds__(256) void fallback_kernel(const float* __restrict__ x,
                                                       const float* __restrict__ iv,
                                                       const float* __restrict__ b,
                                                       float* __restrict__ out) {
  int idx = blockIdx.x * 256 + threadIdx.x;  // B*2048 + o
  int Bn = idx >> 11, o = idx & 2047;
  int f = o >> 4, t = o & 15;
  const float* xr = x + (size_t)Bn * 2048;
  float acc = 0.f;
  for (int g = 0; g < 128; ++g) {
    const float* pr = iv + (f * 128 + g) * 16;
    const float* xg = xr + g * 16;
#pragma unroll
    for (int s = 0; s < 16; ++s) acc += pr[s] * xg[(t - s) & 15];
  }
  out[idx] = acc + b[o];
}

extern "C" void kernel_launch(void* const* d_in, const int* in_sizes, int n_in,
                              void* d_out, int out_size, void* d_ws, size_t ws_size,
                              hipStream_t stream) {
  const float* x    = (const float*)d_in[0];  // [4096][2048] fp32
  const float* iv   = (const float*)d_in[1];  // [128][128][16] fp32
  const float* bias = (const float*)d_in[2];  // [2048] fp32
  float* out = (float*)d_out;                 // [4096][2048] fp32

  const size_t xb_bytes = (size_t)M_DIM * K_DIM * 2;  // 16 MB
  const size_t w_bytes  = (size_t)N_DIM * K_DIM * 2;  //  8 MB
  if (ws_size < xb_bytes + w_bytes) {
    fallback_kernel<<<(M_DIM * N_DIM) / 256, 256, 0, stream>>>(x, iv, bias, out);
    return;
  }

  unsigned short* xb = (unsigned short*)d_ws;
  unsigned short* W  = xb + (size_t)M_DIM * K_DIM;

  cvt_x_kernel<<<(M_DIM * K_DIM / 8) / 256, 256, 0, stream>>>(x, xb);
  build_w_kernel<<<(N_DIM * K_DIM / 8) / 256, 256, 0, stream>>>(iv, W);

  dim3 grid(N_DIM / 128, M_DIM / 128);
  gemm_bias_kernel<<<grid, 256, 0, stream>>>(xb, W, bias, out);
}

// Round 2
// 62.762 us; speedup vs baseline: 1.1109x; 1.1109x over previous
//
#include <hip/hip_runtime.h>
#include <hip/hip_bf16.h>

// EnhancedBCMLayer: block-circulant matmul == dense GEMM
//   out = X (4096x2048) @ W^T (2048x2048) + b, fp32 out
//   W[f*16+t][g*16+u] = iv[f, g, (t-u)&15]
// GEMM: BM=256 x BN=128 x BK=64, 8 waves (4M x 2N), per-wave 64x64,
// counted-vmcnt pipeline + XOR-swizzled LDS (T1+T2+T3+T4+T5).

#define M_DIM 4096
#define N_DIM 2048
#define K_DIM 2048
#define BK 64
#define NT (K_DIM / BK)   // 32 K-tiles

typedef __attribute__((ext_vector_type(8))) short bf16x8;
typedef __attribute__((ext_vector_type(4))) float f32x4;

typedef const __attribute__((address_space(1))) void gvoid_t;
typedef __attribute__((address_space(3))) void lvoid_t;

#define FENCE asm volatile("" ::: "memory")
#define BAR()  do { FENCE; __builtin_amdgcn_s_barrier(); FENCE; } while (0)
#define GLD(src, dst) __builtin_amdgcn_global_load_lds((gvoid_t*)(src), (lvoid_t*)(dst), 16, 0, 0)

// fp32 -> bf16 RNE
__device__ __forceinline__ unsigned int f2bf(float f) {
  unsigned int u = __float_as_uint(f);
  return (u + 0x7fffu + ((u >> 16) & 1u)) >> 16;
}

// ---------------- fused prologue: cvt X -> bf16  |  expand iv -> dense bf16 W [N][K] ----------------
__global__ __launch_bounds__(256) void prep_kernel(const float* __restrict__ x,
                                                   const float* __restrict__ iv,
                                                   unsigned short* __restrict__ xb,
                                                   unsigned short* __restrict__ W) {
  int b = blockIdx.x;
  if (b < (M_DIM * K_DIM / 8) / 256) {
    int idx = b * 256 + threadIdx.x;          // one per 8 floats
    const float4* x4 = (const float4*)x;
    float4 a = x4[idx * 2 + 0];
    float4 c = x4[idx * 2 + 1];
    uint4 o;
    o.x = f2bf(a.x) | (f2bf(a.y) << 16);
    o.y = f2bf(a.z) | (f2bf(a.w) << 16);
    o.z = f2bf(c.x) | (f2bf(c.y) << 16);
    o.w = f2bf(c.z) | (f2bf(c.w) << 16);
    ((uint4*)xb)[idx] = o;
  } else {
    int idx = (b - (M_DIM * K_DIM / 8) / 256) * 256 + threadIdx.x;  // one per 8 weights
    int o  = idx >> 8;             // W row 0..2047
    int i0 = (idx & 255) * 8;      // col start
    int f = o >> 4, t = o & 15;
    int g = i0 >> 4, u0 = i0 & 15;
    const float* row = iv + (f * 128 + g) * 16;
    unsigned int p[4];
#pragma unroll
    for (int j = 0; j < 4; ++j) {
      unsigned int lo = f2bf(row[(t - (u0 + 2 * j + 0)) & 15]);
      unsigned int hi = f2bf(row[(t - (u0 + 2 * j + 1)) & 15]);
      p[j] = lo | (hi << 16);
    }
    ((uint4*)W)[idx] = make_uint4(p[0], p[1], p[2], p[3]);
  }
}

// ---------------- main GEMM ----------------
// LDS map (bytes): A buf c at c*32768 ([256 rows][128B row], XOR-swizzled slots)
//                  B buf c at 65536 + c*16384 ([128 rows][128B row])
__global__ __launch_bounds__(512, 2) void gemm_bias_kernel(const unsigned short* __restrict__ A,
                                                           const unsigned short* __restrict__ B,
                                                           const float* __restrict__ bias,
                                                           float* __restrict__ C) {
  __shared__ char lds[96 * 1024];

  const int tid = threadIdx.x;
  const int l   = tid & 63;
  const int w   = tid >> 6;       // wave 0..7
  const int wm  = w >> 1;         // wave row 0..3 (64 M-rows each)
  const int wn  = w & 1;          // wave col 0..1 (64 N-cols each)

  // XCD-aware bijective swizzle (grid=256, 256%8==0)
  const int orig = blockIdx.x;
  const int swz  = (orig & 7) * 32 + (orig >> 3);
  const int bm   = swz >> 4;      // 0..15  (M tile)
  const int bn   = swz & 15;      // 0..15  (N tile)

  f32x4 acc[4][4] = {};

  // ---- staging addresses (inverse-swizzled global source, linear LDS dest) ----
  // instr j covers tile rows j*64 + w*8 + (l>>3); lane writes LDS slot (l&7).
  const int srow  = w * 8 + (l >> 3);               // 0..63
  const int sslot = (l & 7) ^ ((l >> 3) & 7);       // pre-swizzled K-slot
  const unsigned short* Asrc0 = A + (size_t)(bm * 256 + srow) * K_DIM + sslot * 8;
  const unsigned short* Bsrc0 = B + (size_t)(bn * 128 + srow) * K_DIM + sslot * 8;

  // ---- ds_read addresses (swizzled) ----
  const int fr = l & 15;                            // fragment row within 16
  const int rxor = (l & 7) << 4;                    // row&7 == l&7 for all frags
  const int aRow0 = (wm * 64 + fr) * 128;           // byte row base, + m*2048
  const int bRow0 = (wn * 64 + fr) * 128;           // + n*2048
  const int swzcol0 = (0 * 64 + (l >> 4) * 16) ^ rxor;
  const int swzcol1 = (1 * 64 + (l >> 4) * 16) ^ rxor;

#define STAGE(t)                                                        \
  do {                                                                  \
    const int c_ = (t) & 1;                                             \
    const unsigned short* as_ = Asrc0 + (t) * BK;                       \
    const unsigned short* bs_ = Bsrc0 + (t) * BK;                       \
    char* ad_ = lds + c_ * 32768 + w * 1024;                            \
    char* bd_ = lds + 65536 + c_ * 16384 + w * 1024;                    \
    GLD(as_ + 0 * 64 * K_DIM, ad_ + 0);                                 \
    GLD(as_ + 1 * 64 * K_DIM, ad_ + 8192);                              \
    GLD(as_ + 2 * 64 * K_DIM, ad_ + 16384);                             \
    GLD(as_ + 3 * 64 * K_DIM, ad_ + 24576);                             \
    GLD(bs_ + 0 * 64 * K_DIM, bd_ + 0);                                 \
    GLD(bs_ + 1 * 64 * K_DIM, bd_ + 8192);                              \
  } while (0)

#define PHASE(Ab, Bb, SWZ)                                              \
  do {                                                                  \
    bf16x8 a_[4], b_[4];                                                \
    _Pragma("unroll")                                                   \
    for (int m = 0; m < 4; ++m)                                         \
      a_[m] = *(const bf16x8*)(Ab + aRow0 + m * 2048 + (SWZ));          \
    _Pragma("unroll")                                                   \
    for (int n = 0; n < 4; ++n)                                         \
      b_[n] = *(const bf16x8*)(Bb + bRow0 + n * 2048 + (SWZ));          \
    BAR();                                                              \
    asm volatile("s_waitcnt lgkmcnt(0)" ::: "memory");                  \
    __builtin_amdgcn_sched_barrier(0);                                  \
    __builtin_amdgcn_s_setprio(1);                                      \
    _Pragma("unroll")                                                   \
    for (int m = 0; m < 4; ++m)                                         \
      _Pragma("unroll")                                                 \
      for (int n = 0; n < 4; ++n)                                       \
        acc[m][n] = __builtin_amdgcn_mfma_f32_16x16x32_bf16(a_[m], b_[n], acc[m][n], 0, 0, 0); \
    __builtin_amdgcn_s_setprio(0);                                      \
    __builtin_amdgcn_sched_barrier(0);                                  \
    BAR();                                                              \
  } while (0)

  // prologue: stage tile 0
  STAGE(0);

  for (int t = 0; t < NT - 1; ++t) {
    STAGE(t + 1);                                   // issue BEFORE waiting on tile t
    asm volatile("s_waitcnt vmcnt(6)" ::: "memory"); // tile t done; t+1's 6 still in flight
    BAR();
    const char* Ab = lds + (t & 1) * 32768;
    const char* Bb = lds + 65536 + (t & 1) * 16384;
    PHASE(Ab, Bb, swzcol0);
    PHASE(Ab, Bb, swzcol1);
  }
  // final tile: drain
  asm volatile("s_waitcnt vmcnt(0)" ::: "memory");
  BAR();
  {
    const char* Ab = lds + ((NT - 1) & 1) * 32768;
    const char* Bb = lds + 65536 + ((NT - 1) & 1) * 16384;
    PHASE(Ab, Bb, swzcol0);
    PHASE(Ab, Bb, swzcol1);
  }

  // ---- epilogue: C/D layout col=lane&15, row=(lane>>4)*4+reg ----
  const int row0 = bm * 256 + wm * 64 + (l >> 4) * 4;
  const int col0 = bn * 128 + wn * 64 + (l & 15);
#pragma unroll
  for (int n = 0; n < 4; ++n) {
    float bv = bias[col0 + n * 16];
#pragma unroll
    for (int m = 0; m < 4; ++m) {
#pragma unroll
      for (int j = 0; j < 4; ++j) {
        C[(size_t)(row0 + m * 16 + j) * N_DIM + (col0 + n * 16)] = acc[m][n][j] + bv;
      }
    }
  }
#undef STAGE
#undef PHASE
}

// ---------------- fallback (ws too small): direct fp32 ----------------
__global__ __launch_bounds__(256) void fallback_kernel(const float* __restrict__ x,
                                                       const float* __restrict__ iv,
                                                       const float* __restrict__ b,
                                                       float* __restrict__ out) {
  int idx = blockIdx.x * 256 + threadIdx.x;
  int Bn = idx >> 11, o = idx & 2047;
  int f = o >> 4, t = o & 15;
  const float* xr = x + (size_t)Bn * 2048;
  float acc = 0.f;
  for (int g = 0; g < 128; ++g) {
    const float* pr = iv + (f * 128 + g) * 16;
    const float* xg = xr + g * 16;
#pragma unroll
    for (int s = 0; s < 16; ++s) acc += pr[s] * xg[(t - s) & 15];
  }
  out[idx] = acc + b[o];
}

extern "C" void kernel_launch(void* const* d_in, const int* in_sizes, int n_in,
                              void* d_out, int out_size, void* d_ws, size_t ws_size,
                              hipStream_t stream) {
  const float* x    = (const float*)d_in[0];
  const float* iv   = (const float*)d_in[1];
  const float* bias = (const float*)d_in[2];
  float* out = (float*)d_out;

  const size_t xb_bytes = (size_t)M_DIM * K_DIM * 2;
  const size_t w_bytes  = (size_t)N_DIM * K_DIM * 2;
  if (ws_size < xb_bytes + w_bytes) {
    fallback_kernel<<<(M_DIM * N_DIM) / 256, 256, 0, stream>>>(x, iv, bias, out);
    return;
  }

  unsigned short* xb = (unsigned short*)d_ws;
  unsigned short* W  = xb + (size_t)M_DIM * K_DIM;

  const int cvt_blocks = (M_DIM * K_DIM / 8) / 256;   // 4096
  const int bw_blocks  = (N_DIM * K_DIM / 8) / 256;   // 2048
  prep_kernel<<<cvt_blocks + bw_blocks, 256, 0, stream>>>(x, iv, xb, W);

  gemm_bias_kernel<<<(M_DIM / 256) * (N_DIM / 128), 512, 0, stream>>>(xb, W, bias, out);
}

// Round 3
// 57.207 us; speedup vs baseline: 1.2188x; 1.0971x over previous
//
#include <hip/hip_runtime.h>
#include <hip/hip_bf16.h>

// EnhancedBCMLayer: block-circulant matmul == dense GEMM
//   out = X (4096x2048) @ W^T (2048x2048) + b, fp32 out
//   W[f*16+t][g*16+u] = iv[f, g, (t-u)&15]
// GEMM: BM=256 x BN=128 x BK=64, 8 waves (4M x 2N), per-wave 64x64.
// 3-buffer LDS, 2-K-tile-deep prefetch, per-phase interleaved staging,
// counted vmcnt(6) once per tile (T1+T2+T3+T4+T5).

#define M_DIM 4096
#define N_DIM 2048
#define K_DIM 2048
#define BK 64
#define NT (K_DIM / BK)   // 32 K-tiles
#define BUFSZ 49152       // 48 KB per buffer: A 32 KB + B 16 KB

typedef __attribute__((ext_vector_type(8))) short bf16x8;
typedef __attribute__((ext_vector_type(4))) float f32x4;

typedef const __attribute__((address_space(1))) void gvoid_t;
typedef __attribute__((address_space(3))) void lvoid_t;

#define FENCE asm volatile("" ::: "memory")
#define BAR()  do { FENCE; __builtin_amdgcn_s_barrier(); FENCE; } while (0)
#define GLD(src, dst) __builtin_amdgcn_global_load_lds((gvoid_t*)(src), (lvoid_t*)(dst), 16, 0, 0)

// comma-expression stages (usable as a single macro argument)
#define STAGE_A(dst, src) (GLD((src) + 0 * 64 * K_DIM, (dst) + 0),     \
                           GLD((src) + 1 * 64 * K_DIM, (dst) + 8192),  \
                           GLD((src) + 2 * 64 * K_DIM, (dst) + 16384), \
                           GLD((src) + 3 * 64 * K_DIM, (dst) + 24576))
#define STAGE_B(dst, src) (GLD((src) + 0 * 64 * K_DIM, (dst) + 0),     \
                           GLD((src) + 1 * 64 * K_DIM, (dst) + 8192))

// fp32 -> bf16 RNE
__device__ __forceinline__ unsigned int f2bf(float f) {
  unsigned int u = __float_as_uint(f);
  return (u + 0x7fffu + ((u >> 16) & 1u)) >> 16;
}

// ---------------- fused prologue: cvt X -> bf16  |  expand iv -> dense bf16 W [N][K] ----------------
__global__ __launch_bounds__(256) void prep_kernel(const float* __restrict__ x,
                                                   const float* __restrict__ iv,
                                                   unsigned short* __restrict__ xb,
                                                   unsigned short* __restrict__ W) {
  int b = blockIdx.x;
  if (b < (M_DIM * K_DIM / 8) / 256) {
    int idx = b * 256 + threadIdx.x;          // one per 8 floats
    const float4* x4 = (const float4*)x;
    float4 a = x4[idx * 2 + 0];
    float4 c = x4[idx * 2 + 1];
    uint4 o;
    o.x = f2bf(a.x) | (f2bf(a.y) << 16);
    o.y = f2bf(a.z) | (f2bf(a.w) << 16);
    o.z = f2bf(c.x) | (f2bf(c.y) << 16);
    o.w = f2bf(c.z) | (f2bf(c.w) << 16);
    ((uint4*)xb)[idx] = o;
  } else {
    int idx = (b - (M_DIM * K_DIM / 8) / 256) * 256 + threadIdx.x;  // one per 8 weights
    int o  = idx >> 8;             // W row 0..2047
    int i0 = (idx & 255) * 8;      // col start
    int f = o >> 4, t = o & 15;
    int g = i0 >> 4, u0 = i0 & 15;
    const float* row = iv + (f * 128 + g) * 16;
    unsigned int p[4];
#pragma unroll
    for (int j = 0; j < 4; ++j) {
      unsigned int lo = f2bf(row[(t - (u0 + 2 * j + 0)) & 15]);
      unsigned int hi = f2bf(row[(t - (u0 + 2 * j + 1)) & 15]);
      p[j] = lo | (hi << 16);
    }
    ((uint4*)W)[idx] = make_uint4(p[0], p[1], p[2], p[3]);
  }
}

// ---------------- main GEMM ----------------
// LDS: 3 buffers of 48 KB: buf c at c*49152, A [256 rows][128B], B at +32768 [128 rows][128B].
// XOR-swizzle byte ^= (row&7)<<4 on both the GLD global source and the ds_read col.
__global__ __launch_bounds__(512, 2) void gemm_bias_kernel(const unsigned short* __restrict__ A,
                                                           const unsigned short* __restrict__ B,
                                                           const float* __restrict__ bias,
                                                           float* __restrict__ C) {
  __shared__ char lds[3 * BUFSZ];   // 144 KB

  const int tid = threadIdx.x;
  const int l   = tid & 63;
  const int w   = tid >> 6;       // wave 0..7
  const int wm  = w >> 1;         // wave row 0..3 (64 M-rows each)
  const int wn  = w & 1;          // wave col 0..1 (64 N-cols each)

  // XCD-aware bijective swizzle (grid=256, 256%8==0)
  const int orig = blockIdx.x;
  const int swz  = (orig & 7) * 32 + (orig >> 3);
  const int bm   = swz >> 4;      // 0..15  (M tile)
  const int bn   = swz & 15;      // 0..15  (N tile)

  f32x4 acc[4][4] = {};

  // ---- staging addresses (inverse-swizzled global source, linear LDS dest) ----
  // GLD j covers rows j*64 + w*8 + (l>>3); lane writes LDS 16B-slot (l&7).
  const int srow  = w * 8 + (l >> 3);               // 0..63
  const int sslot = (l & 7) ^ ((l >> 3) & 7);       // pre-swizzled K-slot
  const unsigned short* Asrc0 = A + (size_t)(bm * 256 + srow) * K_DIM + sslot * 8;
  const unsigned short* Bsrc0 = B + (size_t)(bn * 128 + srow) * K_DIM + sslot * 8;

  // ---- ds_read addresses (swizzled) ----
  const int fr = l & 15;                            // fragment row within 16
  const int rxor = (l & 7) << 4;                    // (row&7)<<4, same for all frags
  const int aRow0 = (wm * 64 + fr) * 128;           // byte row base, + m*2048
  const int bRow0 = (wn * 64 + fr) * 128;           // + n*2048
  const int swzcol0 = (0 * 64 + (l >> 4) * 16) ^ rxor;  // K 0..31
  const int swzcol1 = (1 * 64 + (l >> 4) * 16) ^ rxor;  // K 32..63

#define PHASE(Ab, Bb, SWZ, STAGE_STMT)                                  \
  do {                                                                  \
    bf16x8 a_[4], b_[4];                                                \
    _Pragma("unroll")                                                   \
    for (int m = 0; m < 4; ++m)                                         \
      a_[m] = *(const bf16x8*)((Ab) + aRow0 + m * 2048 + (SWZ));        \
    _Pragma("unroll")                                                   \
    for (int n = 0; n < 4; ++n)                                         \
      b_[n] = *(const bf16x8*)((Bb) + bRow0 + n * 2048 + (SWZ));        \
    STAGE_STMT;                                                         \
    BAR();                                                              \
    asm volatile("s_waitcnt lgkmcnt(0)" ::: "memory");                  \
    __builtin_amdgcn_sched_barrier(0);                                  \
    __builtin_amdgcn_s_setprio(1);                                      \
    _Pragma("unroll")                                                   \
    for (int m = 0; m < 4; ++m)                                         \
      _Pragma("unroll")                                                 \
      for (int n = 0; n < 4; ++n)                                       \
        acc[m][n] = __builtin_amdgcn_mfma_f32_16x16x32_bf16(a_[m], b_[n], acc[m][n], 0, 0, 0); \
    __builtin_amdgcn_s_setprio(0);                                      \
    __builtin_amdgcn_sched_barrier(0);                                  \
    BAR();                                                              \
  } while (0)

  // Full tile: compute buf CUR_, stage tile t_+2 into buf NB_, then ensure t_+1 ready.
#define TILE_T(t_, CUR_, NB_)                                           \
  do {                                                                  \
    const char* Ab = lds + (CUR_) * BUFSZ;                              \
    const char* Bb = Ab + 32768;                                        \
    char* Ad = lds + (NB_) * BUFSZ + w * 1024;                          \
    char* Bd = lds + (NB_) * BUFSZ + 32768 + w * 1024;                  \
    const unsigned short* as2 = Asrc0 + ((t_) + 2) * BK;                \
    const unsigned short* bs2 = Bsrc0 + ((t_) + 2) * BK;                \
    PHASE(Ab, Bb, swzcol0, STAGE_A(Ad, as2));                           \
    PHASE(Ab, Bb, swzcol1, STAGE_B(Bd, bs2));                           \
    asm volatile("s_waitcnt vmcnt(6)" ::: "memory");                    \
    BAR();                                                              \
  } while (0)

  // ---- prologue: stage tiles 0 and 1 ----
  STAGE_A(lds + 0 * BUFSZ + w * 1024, Asrc0 + 0 * BK);
  STAGE_B(lds + 0 * BUFSZ + 32768 + w * 1024, Bsrc0 + 0 * BK);
  STAGE_A(lds + 1 * BUFSZ + w * 1024, Asrc0 + 1 * BK);
  STAGE_B(lds + 1 * BUFSZ + 32768 + w * 1024, Bsrc0 + 1 * BK);
  asm volatile("s_waitcnt vmcnt(6)" ::: "memory");  // tile 0 landed; tile 1 in flight
  BAR();

  // ---- main loop: tiles 0..29 (unroll x3 for compile-time buffer indices) ----
  for (int t = 0; t < NT - 2; t += 3) {
    TILE_T(t + 0, 0, 2);
    TILE_T(t + 1, 1, 0);
    TILE_T(t + 2, 2, 1);
  }

  // ---- tail: tile 30 (buf 0), then tile 31 (buf 1) ----
  {
    const char* Ab = lds + 0 * BUFSZ;
    const char* Bb = Ab + 32768;
    PHASE(Ab, Bb, swzcol0, (void)0);
    PHASE(Ab, Bb, swzcol1, (void)0);
    asm volatile("s_waitcnt vmcnt(0)" ::: "memory");  // tile 31 landed
    BAR();
  }
  {
    const char* Ab = lds + 1 * BUFSZ;
    const char* Bb = Ab + 32768;
    PHASE(Ab, Bb, swzcol0, (void)0);
    PHASE(Ab, Bb, swzcol1, (void)0);
  }

  // ---- epilogue: C/D layout col=lane&15, row=(lane>>4)*4+reg ----
  const int row0 = bm * 256 + wm * 64 + (l >> 4) * 4;
  const int col0 = bn * 128 + wn * 64 + (l & 15);
#pragma unroll
  for (int n = 0; n < 4; ++n) {
    float bv = bias[col0 + n * 16];
#pragma unroll
    for (int m = 0; m < 4; ++m) {
#pragma unroll
      for (int j = 0; j < 4; ++j) {
        C[(size_t)(row0 + m * 16 + j) * N_DIM + (col0 + n * 16)] = acc[m][n][j] + bv;
      }
    }
  }
#undef TILE_T
#undef PHASE
}

// ---------------- fallback (ws too small): direct fp32 ----------------
__global__ __launch_bounds__(256) void fallback_kernel(const float* __restrict__ x,
                                                       const float* __restrict__ iv,
                                                       const float* __restrict__ b,
                                                       float* __restrict__ out) {
  int idx = blockIdx.x * 256 + threadIdx.x;
  int Bn = idx >> 11, o = idx & 2047;
  int f = o >> 4, t = o & 15;
  const float* xr = x + (size_t)Bn * 2048;
  float acc = 0.f;
  for (int g = 0; g < 128; ++g) {
    const float* pr = iv + (f * 128 + g) * 16;
    const float* xg = xr + g * 16;
#pragma unroll
    for (int s = 0; s < 16; ++s) acc += pr[s] * xg[(t - s) & 15];
  }
  out[idx] = acc + b[o];
}

extern "C" void kernel_launch(void* const* d_in, const int* in_sizes, int n_in,
                              void* d_out, int out_size, void* d_ws, size_t ws_size,
                              hipStream_t stream) {
  const float* x    = (const float*)d_in[0];
  const float* iv   = (const float*)d_in[1];
  const float* bias = (const float*)d_in[2];
  float* out = (float*)d_out;

  const size_t xb_bytes = (size_t)M_DIM * K_DIM * 2;
  const size_t w_bytes  = (size_t)N_DIM * K_DIM * 2;
  if (ws_size < xb_bytes + w_bytes) {
    fallback_kernel<<<(M_DIM * N_DIM) / 256, 256, 0, stream>>>(x, iv, bias, out);
    return;
  }

  unsigned short* xb = (unsigned short*)d_ws;
  unsigned short* W  = xb + (size_t)M_DIM * K_DIM;

  const int cvt_blocks = (M_DIM * K_DIM / 8) / 256;   // 4096
  const int bw_blocks  = (N_DIM * K_DIM / 8) / 256;   // 2048
  prep_kernel<<<cvt_blocks + bw_blocks, 256, 0, stream>>>(x, iv, xb, W);

  gemm_bias_kernel<<<(M_DIM / 256) * (N_DIM / 128), 512, 0, stream>>>(xb, W, bias, out);
}

// Round 4
// 55.096 us; speedup vs baseline: 1.2655x; 1.0383x over previous
//
#include <hip/hip_runtime.h>
#include <hip/hip_bf16.h>

// EnhancedBCMLayer: block-circulant matmul == dense GEMM
//   out = X (4096x2048) @ W^T (2048x2048) + b, fp32 out
//   W[f*16+t][g*16+u] = iv[f, g, (t-u)&15]
// GEMM: BM=256 x BN=128 x BK=64, 8 waves (4M x 2N), per-wave 64x64.
// 3-buffer LDS, 2-tile-deep GLD prefetch, CROSS-PHASE register prefetch
// (ping-pong fragment sets, counted lgkmcnt(8)), 2 barriers/tile.
// T1 XCD swizzle + T2 LDS XOR swizzle + T4 counted vmcnt + T5 setprio.

#define M_DIM 4096
#define N_DIM 2048
#define K_DIM 2048
#define BK 64
#define NT (K_DIM / BK)   // 32 K-tiles
#define BUFSZ 49152       // 48 KB per buffer: A 32 KB + B 16 KB

typedef __attribute__((ext_vector_type(8))) short bf16x8;
typedef __attribute__((ext_vector_type(4))) float f32x4;

typedef const __attribute__((address_space(1))) void gvoid_t;
typedef __attribute__((address_space(3))) void lvoid_t;

#define FENCE asm volatile("" ::: "memory")
#define BAR()  do { FENCE; __builtin_amdgcn_s_barrier(); FENCE; } while (0)
#define GLD(src, dst) __builtin_amdgcn_global_load_lds((gvoid_t*)(src), (lvoid_t*)(dst), 16, 0, 0)

// issue-order matters for vmcnt counting: A = 4 GLD, B = 2 GLD
#define STAGE_A(dst, src) (GLD((src) + 0 * 64 * K_DIM, (dst) + 0),     \
                           GLD((src) + 1 * 64 * K_DIM, (dst) + 8192),  \
                           GLD((src) + 2 * 64 * K_DIM, (dst) + 16384), \
                           GLD((src) + 3 * 64 * K_DIM, (dst) + 24576))
#define STAGE_B(dst, src) (GLD((src) + 0 * 64 * K_DIM, (dst) + 0),     \
                           GLD((src) + 1 * 64 * K_DIM, (dst) + 8192))

// fp32 -> bf16 RNE
__device__ __forceinline__ unsigned int f2bf(float f) {
  unsigned int u = __float_as_uint(f);
  return (u + 0x7fffu + ((u >> 16) & 1u)) >> 16;
}

// ---------------- fused prologue: cvt X -> bf16  |  expand iv -> dense bf16 W [N][K] ----------------
__global__ __launch_bounds__(256) void prep_kernel(const float* __restrict__ x,
                                                   const float* __restrict__ iv,
                                                   unsigned short* __restrict__ xb,
                                                   unsigned short* __restrict__ W) {
  int b = blockIdx.x;
  if (b < (M_DIM * K_DIM / 8) / 256) {
    int idx = b * 256 + threadIdx.x;          // one per 8 floats
    const float4* x4 = (const float4*)x;
    float4 a = x4[idx * 2 + 0];
    float4 c = x4[idx * 2 + 1];
    uint4 o;
    o.x = f2bf(a.x) | (f2bf(a.y) << 16);
    o.y = f2bf(a.z) | (f2bf(a.w) << 16);
    o.z = f2bf(c.x) | (f2bf(c.y) << 16);
    o.w = f2bf(c.z) | (f2bf(c.w) << 16);
    ((uint4*)xb)[idx] = o;
  } else {
    int idx = (b - (M_DIM * K_DIM / 8) / 256) * 256 + threadIdx.x;  // one per 8 weights
    int o  = idx >> 8;             // W row 0..2047
    int i0 = (idx & 255) * 8;      // col start
    int f = o >> 4, t = o & 15;
    int g = i0 >> 4, u0 = i0 & 15;
    const float* row = iv + (f * 128 + g) * 16;
    unsigned int p[4];
#pragma unroll
    for (int j = 0; j < 4; ++j) {
      unsigned int lo = f2bf(row[(t - (u0 + 2 * j + 0)) & 15]);
      unsigned int hi = f2bf(row[(t - (u0 + 2 * j + 1)) & 15]);
      p[j] = lo | (hi << 16);
    }
    ((uint4*)W)[idx] = make_uint4(p[0], p[1], p[2], p[3]);
  }
}

// ---------------- main GEMM ----------------
// LDS: 3 buffers of 48 KB: buf c at c*49152, A [256 rows][128B], B at +32768 [128 rows][128B].
// XOR-swizzle byte ^= (row&7)<<4 on both the GLD global source and the ds_read col.
__global__ __launch_bounds__(512, 2) void gemm_bias_kernel(const unsigned short* __restrict__ A,
                                                           const unsigned short* __restrict__ B,
                                                           const float* __restrict__ bias,
                                                           float* __restrict__ C) {
  __shared__ char lds[3 * BUFSZ];   // 144 KB

  const int tid = threadIdx.x;
  const int l   = tid & 63;
  const int w   = tid >> 6;       // wave 0..7
  const int wm  = w >> 1;         // wave row 0..3 (64 M-rows each)
  const int wn  = w & 1;          // wave col 0..1 (64 N-cols each)

  // XCD-aware bijective swizzle (grid=256, 256%8==0)
  const int orig = blockIdx.x;
  const int swz  = (orig & 7) * 32 + (orig >> 3);
  const int bm   = swz >> 4;      // 0..15  (M tile)
  const int bn   = swz & 15;      // 0..15  (N tile)

  f32x4 acc[4][4] = {};

  // ---- staging addresses (inverse-swizzled global source, linear LDS dest) ----
  // GLD j covers rows j*64 + w*8 + (l>>3); lane writes LDS 16B-slot (l&7).
  const int srow  = w * 8 + (l >> 3);               // 0..63
  const int sslot = (l & 7) ^ ((l >> 3) & 7);       // pre-swizzled K-slot
  const unsigned short* Asrc0 = A + (size_t)(bm * 256 + srow) * K_DIM + sslot * 8;
  const unsigned short* Bsrc0 = B + (size_t)(bn * 128 + srow) * K_DIM + sslot * 8;

  // ---- ds_read addresses (swizzled) ----
  const int fr = l & 15;                            // fragment row within 16
  const int rxor = (l & 7) << 4;                    // (row&7)<<4, same for all frags
  const int aRow0 = (wm * 64 + fr) * 128;           // byte row base, + m*2048
  const int bRow0 = (wn * 64 + fr) * 128;           // + n*2048
  const int swzcol0 = (0 * 64 + (l >> 4) * 16) ^ rxor;  // K 0..31
  const int swzcol1 = (1 * 64 + (l >> 4) * 16) ^ rxor;  // K 32..63

  // ping-pong fragment sets: set0 consumed by P0-MFMA, set1 by P1-MFMA
  bf16x8 fa0[4], fb0[4], fa1[4], fb1[4];

  // issue 8 ds_reads for one fragment set from buffer BUF at column swizzle SWZ
#define LDA(SA, SB, BUF, SWZ)                                           \
  do {                                                                  \
    const char* Ab_ = lds + (BUF) * BUFSZ;                              \
    const char* Bb_ = Ab_ + 32768;                                      \
    _Pragma("unroll")                                                   \
    for (int m = 0; m < 4; ++m)                                         \
      SA[m] = *(const bf16x8*)(Ab_ + aRow0 + m * 2048 + (SWZ));         \
    _Pragma("unroll")                                                   \
    for (int n = 0; n < 4; ++n)                                         \
      SB[n] = *(const bf16x8*)(Bb_ + bRow0 + n * 2048 + (SWZ));         \
  } while (0)

  // counted-lgkm MFMA cluster: waits only for reads older than the CNT newest
#define MM(SA, SB, CNT)                                                 \
  do {                                                                  \
    asm volatile("s_waitcnt lgkmcnt(" #CNT ")" ::: "memory");           \
    __builtin_amdgcn_sched_barrier(0);                                  \
    __builtin_amdgcn_s_setprio(1);                                      \
    _Pragma("unroll")                                                   \
    for (int m = 0; m < 4; ++m)                                         \
      _Pragma("unroll")                                                 \
      for (int n = 0; n < 4; ++n)                                       \
        acc[m][n] = __builtin_amdgcn_mfma_f32_16x16x32_bf16(SA[m], SB[n], acc[m][n], 0, 0, 0); \
    __builtin_amdgcn_s_setprio(0);                                      \
    __builtin_amdgcn_sched_barrier(0);                                  \
  } while (0)

  // Steady-state tile t: buffers CUR=t%3, NXT=(t+1)%3, STG=(t+2)%3.
  // P0: load set1 (this tile, K 32..63) | stage A(t+2) | MFMA set0 (K 0..31)
  //     vmcnt(4): tile t+1 fully landed (A(t+2)'s 4 loads stay in flight); barrier
  // P1: load set0 (tile t+1, K 0..31, early-read of buf NXT) | stage B(t+2) | MFMA set1
  //     barrier (releases buf STG' writes at t+1.P0 after all reads done)
#define TILE_FULL(CUR, NXT, STG, T)                                     \
  do {                                                                  \
    LDA(fa1, fb1, CUR, swzcol1);                                        \
    STAGE_A(lds + (STG) * BUFSZ + w * 1024, Asrc0 + ((T) + 2) * BK);    \
    MM(fa0, fb0, 8);                                                    \
    asm volatile("s_waitcnt vmcnt(4)" ::: "memory");                    \
    BAR();                                                              \
    LDA(fa0, fb0, NXT, swzcol0);                                        \
    STAGE_B(lds + (STG) * BUFSZ + 32768 + w * 1024, Bsrc0 + ((T) + 2) * BK); \
    MM(fa1, fb1, 8);                                                    \
    BAR();                                                              \
  } while (0)

  // ---- prologue: stage tiles 0 and 1 (same per-wave issue order as steady state) ----
  STAGE_A(lds + 0 * BUFSZ + w * 1024, Asrc0 + 0 * BK);
  STAGE_B(lds + 0 * BUFSZ + 32768 + w * 1024, Bsrc0 + 0 * BK);
  STAGE_A(lds + 1 * BUFSZ + w * 1024, Asrc0 + 1 * BK);
  STAGE_B(lds + 1 * BUFSZ + 32768 + w * 1024, Bsrc0 + 1 * BK);
  asm volatile("s_waitcnt vmcnt(6)" ::: "memory");  // tile 0 landed; tile 1 in flight
  BAR();
  LDA(fa0, fb0, 0, swzcol0);                        // preload set0 for tile 0 P0

  // ---- main loop: tiles 0..29 (unroll x3 for compile-time buffer indices) ----
  for (int t = 0; t < NT - 2; t += 3) {
    TILE_FULL(0, 1, 2, t);
    TILE_FULL(1, 2, 0, t + 1);
    TILE_FULL(2, 0, 1, t + 2);
  }

  // ---- tail: tile 30 (buf 0, no staging; vmcnt(0) ensures tile 31 landed) ----
  LDA(fa1, fb1, 0, swzcol1);
  MM(fa0, fb0, 8);
  asm volatile("s_waitcnt vmcnt(0)" ::: "memory");
  BAR();
  LDA(fa0, fb0, 1, swzcol0);
  MM(fa1, fb1, 8);
  // ---- tile 31 (buf 1): no barriers needed, drain lgkm at the end ----
  LDA(fa1, fb1, 1, swzcol1);
  MM(fa0, fb0, 8);
  MM(fa1, fb1, 0);

  // ---- epilogue: C/D layout col=lane&15, row=(lane>>4)*4+reg ----
  const int row0 = bm * 256 + wm * 64 + (l >> 4) * 4;
  const int col0 = bn * 128 + wn * 64 + (l & 15);
#pragma unroll
  for (int n = 0; n < 4; ++n) {
    float bv = bias[col0 + n * 16];
#pragma unroll
    for (int m = 0; m < 4; ++m) {
#pragma unroll
      for (int j = 0; j < 4; ++j) {
        C[(size_t)(row0 + m * 16 + j) * N_DIM + (col0 + n * 16)] = acc[m][n][j] + bv;
      }
    }
  }
#undef TILE_FULL
#undef MM
#undef LDA
}

// ---------------- fallback (ws too small): direct fp32 ----------------
__global__ __launch_bounds__(256) void fallback_kernel(const float* __restrict__ x,
                                                       const float* __restrict__ iv,
                                                       const float* __restrict__ b,
                                                       float* __restrict__ out) {
  int idx = blockIdx.x * 256 + threadIdx.x;
  int Bn = idx >> 11, o = idx & 2047;
  int f = o >> 4, t = o & 15;
  const float* xr = x + (size_t)Bn * 2048;
  float acc = 0.f;
  for (int g = 0; g < 128; ++g) {
    const float* pr = iv + (f * 128 + g) * 16;
    const float* xg = xr + g * 16;
#pragma unroll
    for (int s = 0; s < 16; ++s) acc += pr[s] * xg[(t - s) & 15];
  }
  out[idx] = acc + b[o];
}

extern "C" void kernel_launch(void* const* d_in, const int* in_sizes, int n_in,
                              void* d_out, int out_size, void* d_ws, size_t ws_size,
                              hipStream_t stream) {
  const float* x    = (const float*)d_in[0];
  const float* iv   = (const float*)d_in[1];
  const float* bias = (const float*)d_in[2];
  float* out = (float*)d_out;

  const size_t xb_bytes = (size_t)M_DIM * K_DIM * 2;
  const size_t w_bytes  = (size_t)N_DIM * K_DIM * 2;
  if (ws_size < xb_bytes + w_bytes) {
    fallback_kernel<<<(M_DIM * N_DIM) / 256, 256, 0, stream>>>(x, iv, bias, out);
    return;
  }

  unsigned short* xb = (unsigned short*)d_ws;
  unsigned short* W  = xb + (size_t)M_DIM * K_DIM;

  const int cvt_blocks = (M_DIM * K_DIM / 8) / 256;   // 4096
  const int bw_blocks  = (N_DIM * K_DIM / 8) / 256;   // 2048
  prep_kernel<<<cvt_blocks + bw_blocks, 256, 0, stream>>>(x, iv, xb, W);

  gemm_bias_kernel<<<(M_DIM / 256) * (N_DIM / 128), 512, 0, stream>>>(xb, W, bias, out);
}